// Round 15
// baseline (427.994 us; speedup 1.0000x reference)
//
#include <hip/hip_runtime.h>
#include <hip/hip_bf16.h>
#include <math.h>

// ---------------------------------------------------------------------------
// ChunkGatedAttentionUnit: B=2, S=4096, H=1024, D=2048, CHUNK=128, nC=32
// Round 15: R14 base (best, all GEMMs coreTB 2 blk/CU) +
//   - gemm2 XCD-pinned nb (Vt slab L2-resident; isolated from R13's NT)
//   - single fused prep kernel (hs cvt + 5 W transposes)
// ---------------------------------------------------------------------------

typedef __bf16 bf16_t;
typedef __bf16 bf16x8 __attribute__((ext_vector_type(8)));
typedef __bf16 bf16x4 __attribute__((ext_vector_type(4)));
typedef float f32x4 __attribute__((ext_vector_type(4)));

#define NB_ 2
#define SEQ 4096
#define HID 1024
#define DD 2048
#define BS 8192
#define LDS_TB 73728  // 3 x 24KB buffers; all stagings fit

__device__ __forceinline__ void async16(const void* g, void* l) {
  __builtin_amdgcn_global_load_lds(
      (const __attribute__((address_space(1))) void*)g,
      (__attribute__((address_space(3))) void*)l, 16, 0, 0);
}

#define VMW0 asm volatile("s_waitcnt vmcnt(0)" ::: "memory")
#define BARR __builtin_amdgcn_s_barrier()
#define FEN asm volatile("" ::: "memory")

// coreTB<WM,WN>: C[M=WM*64, N=WN*64] = A[M,K] @ B[N,K]^T, BK=32.
// 3 LDS buffers of [A: M*32][B: N*32] elems; k-slot swizzle (g+(r>>1))&3 with
// inverse folded into global src. Tile tt issued at iter tt-2; confirmed by
// counted vmcnt(NISS) at iter tt; ONE barrier per iter.
// C mapping: row = (w/WN)*64 + mf*16 + lg*4 + reg, col = (w%WN)*64 + nf*16+lr.
template <int WM, int WN>
__device__ __forceinline__ void coreTB(const bf16_t* __restrict__ A, int lda,
                                       const bf16_t* __restrict__ B, int ldb, int nt,
                                       bf16_t* lds, f32x4 (&acc)[4][4]) {
  constexpr int T = WM * WN * 64;
  constexpr int AE = WM * 64 * 32;
  constexpr int BUF = AE + WN * 64 * 32;
  constexpr int NISS = BUF / (T * 8);
  const int t = threadIdx.x;
  const int lane = t & 63, w = t >> 6;
  const int wm = w / WN, wn = w % WN;
  const int lr = lane & 15, lg = lane >> 4;

  int aOff[4], bOff[4];
#pragma unroll
  for (int f = 0; f < 4; ++f) {
    int ra = wm * 64 + f * 16 + lr;
    aOff[f] = ra * 32 + (((lg + (ra >> 1)) & 3) << 3);
    int rb = wn * 64 + f * 16 + lr;
    bOff[f] = AE + rb * 32 + (((lg + (rb >> 1)) & 3) << 3);
  }
  int src[NISS];
#pragma unroll
  for (int q = 0; q < NISS; ++q) {
    int e = q * T * 8 + t * 8;
    bool isB = (q * T * 8) >= AE;
    int e2 = isB ? e - AE : e;
    int r = e2 >> 5;
    int g = (((e2 >> 3) & 3) - (r >> 1)) & 3;
    src[q] = r * (isB ? ldb : lda) + g * 8;
  }
#pragma unroll
  for (int m = 0; m < 4; ++m)
#pragma unroll
    for (int n = 0; n < 4; ++n) acc[m][n] = (f32x4){0.f, 0.f, 0.f, 0.f};

#pragma unroll
  for (int q = 0; q < NISS; ++q) {
    bool isB = (q * T * 8) >= AE;
    async16((isB ? B : A) + src[q], lds + q * T * 8 + t * 8);
  }
  {
    const int k1 = (1 < nt ? 1 : 0) << 5;
#pragma unroll
    for (int q = 0; q < NISS; ++q) {
      bool isB = (q * T * 8) >= AE;
      async16((isB ? B : A) + k1 + src[q], lds + BUF + q * T * 8 + t * 8);
    }
  }

  for (int tt = 0; tt < nt; ++tt) {
    bf16_t* cur = lds + (tt % 3) * BUF;
    bf16_t* nxt = lds + ((tt + 2) % 3) * BUF;
    const int kn = (tt + 2 < nt ? tt + 2 : 0) << 5;
    if constexpr (NISS == 3) {
      asm volatile("s_waitcnt vmcnt(3)" ::: "memory");
    } else if constexpr (NISS == 4) {
      asm volatile("s_waitcnt vmcnt(4)" ::: "memory");
    } else {
      asm volatile("s_waitcnt vmcnt(0)" ::: "memory");
    }
    BARR; FEN;
    bf16x8 af[4], bv[4];
#pragma unroll
    for (int f = 0; f < 4; ++f) af[f] = *reinterpret_cast<const bf16x8*>(&cur[aOff[f]]);
#pragma unroll
    for (int f = 0; f < 4; ++f) bv[f] = *reinterpret_cast<const bf16x8*>(&cur[bOff[f]]);
#pragma unroll
    for (int q = 0; q < NISS; ++q) {
      bool isB = (q * T * 8) >= AE;
      async16((isB ? B : A) + kn + src[q], nxt + q * T * 8 + t * 8);
    }
    __builtin_amdgcn_s_setprio(1);
#pragma unroll
    for (int mf = 0; mf < 4; ++mf)
#pragma unroll
      for (int nf = 0; nf < 4; ++nf)
        acc[mf][nf] =
            __builtin_amdgcn_mfma_f32_16x16x32_bf16(af[mf], bv[nf], acc[mf][nf], 0, 0, 0);
    __builtin_amdgcn_s_setprio(0);
  }
  VMW0;
  BARR; FEN;
}

// --- fused prep: z<4: W{q,k,v,g} transpose; z==4: Wo transpose; z==5: hs cvt
__global__ void k_prep(const float* __restrict__ hs, const float* __restrict__ W0,
                       const float* __restrict__ W1, const float* __restrict__ W2,
                       const float* __restrict__ W3, const float* __restrict__ Wo,
                       bf16_t* __restrict__ hsb, bf16_t* __restrict__ Wt4,
                       bf16_t* __restrict__ Wot) {
  int z = blockIdx.z;
  int t = threadIdx.x;
  if (z == 5) {  // hs convert: 32x32 blocks x 256 thr x 8 float4
    const float4* in4 = (const float4*)hs;
    bf16x4* out4 = (bf16x4*)hsb;
    int base = (blockIdx.y * 32 + blockIdx.x) * 256 + t;
#pragma unroll
    for (int j = 0; j < 8; ++j) {
      int i = base + j * 262144;
      float4 v = in4[i];
      bf16x4 o;
      o[0] = (bf16_t)v.x; o[1] = (bf16_t)v.y; o[2] = (bf16_t)v.z; o[3] = (bf16_t)v.w;
      out4[i] = o;
    }
    return;
  }
  __shared__ bf16_t tile[64][65];
  int c = t & 63, r0 = t >> 6;
  if (z < 4) {  // W [HID][DD] -> Wt4[z] [DD][HID]
    if (blockIdx.y >= 16) return;
    const float* in = z == 0 ? W0 : z == 1 ? W1 : z == 2 ? W2 : W3;
    bf16_t* o = Wt4 + (long)z * DD * HID;
    int bc = blockIdx.x, br = blockIdx.y;
#pragma unroll
    for (int rr = 0; rr < 64; rr += 4) {
      int r = rr + r0;
      tile[r][c] = (bf16_t)in[(long)(br * 64 + r) * DD + bc * 64 + c];
    }
    __syncthreads();
#pragma unroll
    for (int rr = 0; rr < 64; rr += 4) {
      int r = rr + r0;
      o[(long)(bc * 64 + r) * HID + br * 64 + c] = tile[c][r];
    }
  } else {  // z==4: Wo [DD][HID] -> Wot [HID][DD]
    if (blockIdx.x >= 16) return;
    int bc = blockIdx.x, br = blockIdx.y;
#pragma unroll
    for (int rr = 0; rr < 64; rr += 4) {
      int r = rr + r0;
      tile[r][c] = (bf16_t)Wo[(long)(br * 64 + r) * HID + bc * 64 + c];
    }
    __syncthreads();
#pragma unroll
    for (int rr = 0; rr < 64; rr += 4) {
      int r = rr + r0;
      Wot[(long)(bc * 64 + r) * DD + br * 64 + c] = tile[c][r];
    }
  }
}

// --- GEMM1: QKVG = hsb @ Wt^T + bias; sigmoid z==3; z==2 -> Vt (transposed) -
__global__ __launch_bounds__(512, 4) void k_gemm_qkvg(
    const bf16_t* __restrict__ hsb, const bf16_t* __restrict__ Wt4,
    const float* __restrict__ bq, const float* __restrict__ bk,
    const float* __restrict__ bv, const float* __restrict__ bg,
    bf16_t* __restrict__ out, bf16_t* __restrict__ Vt) {
  extern __shared__ bf16_t lds[];
  const int SP = 136;   // row-major staging stride
  const int SPT = 264;  // transposed staging stride
  int i = blockIdx.x;
  int xcd = i & 7, g = i >> 3;
  int mb = g >> 3;             // 0..31 (256-row tiles)
  int nb = xcd * 8 + (g & 7);  // 0..63 (128-col tiles)
  f32x4 acc[4][4];
  coreTB<4, 2>(hsb + (long)mb * 256 * HID, HID, Wt4 + (long)nb * 128 * HID, HID,
               HID / 32, lds, acc);
  const int t = threadIdx.x, lane = t & 63, w = t >> 6;
  const int wm = w >> 1, wn = w & 1, lr = lane & 15, lg = lane >> 4;
  int z = nb >> 4;
  const float* bias = z == 0 ? bq : z == 1 ? bk : z == 2 ? bv : bg;
  int colT = (nb & 15) * 128;
  float b4[4];
#pragma unroll
  for (int nf = 0; nf < 4; ++nf) b4[nf] = bias[colT + wn * 64 + nf * 16 + lr];
  if (z != 2) {
#pragma unroll
    for (int mf = 0; mf < 4; ++mf)
#pragma unroll
      for (int reg = 0; reg < 4; ++reg) {
        int lrow = wm * 64 + mf * 16 + lg * 4 + reg;
#pragma unroll
        for (int nf = 0; nf < 4; ++nf) {
          float v = acc[mf][nf][reg] + b4[nf];
          if (z == 3) v = 1.f / (1.f + __expf(-v));
          lds[lrow * SP + wn * 64 + nf * 16 + lr] = (bf16_t)v;
        }
      }
    __syncthreads();
    bf16_t* O = out + (long)z * BS * DD + (long)mb * 256 * DD + colT;
#pragma unroll
    for (int it = 0; it < 8; ++it) {
      int s = it * 512 + t;
      int row = s >> 4, sg = s & 15;
      bf16x8 v = *reinterpret_cast<const bf16x8*>(&lds[row * SP + sg * 8]);
      *reinterpret_cast<bf16x8*>(&O[(long)row * DD + sg * 8]) = v;
    }
  } else {
    // TRANSPOSED staging (128 x 264): ldsT[d][s]
#pragma unroll
    for (int mf = 0; mf < 4; ++mf)
#pragma unroll
      for (int reg = 0; reg < 4; ++reg) {
        int lrow = wm * 64 + mf * 16 + lg * 4 + reg;
#pragma unroll
        for (int nf = 0; nf < 4; ++nf) {
          int d = wn * 64 + nf * 16 + lr;
          lds[d * SPT + lrow] = (bf16_t)(acc[mf][nf][reg] + b4[nf]);
        }
      }
    __syncthreads();
    int bz = mb >> 4, smb = mb & 15;
    bf16_t* Vd = Vt + ((long)bz * DD + colT) * SEQ + smb * 256;
#pragma unroll
    for (int it = 0; it < 8; ++it) {
      int s = it * 512 + t;
      int d = s >> 5, sg = s & 31;
      bf16x8 v = *reinterpret_cast<const bf16x8*>(&lds[d * SPT + sg * 8]);
      *reinterpret_cast<bf16x8*>(&Vd[(long)d * SEQ + sg * 8]) = v;
    }
  }
}

// --- pair (coreTB<2,4>): fused diag softmax ---------------------------------
__global__ __launch_bounds__(512, 4) void k_pair(const bf16_t* __restrict__ Q,
                                                 const bf16_t* __restrict__ Kb,
                                                 bf16_t* __restrict__ P) {
  extern __shared__ bf16_t lds[];
  int p = blockIdx.x, b = blockIdx.y;
  int c = 0, base = 0;
  while (base + (c >> 1) + 1 <= p) { base += (c >> 1) + 1; ++c; }
  int jt = p - base;  // jt in [0, (c>>1)]
  f32x4 acc[4][4];
  coreTB<2, 4>(Q + ((long)b * SEQ + (long)c * 128) * DD, DD,
               Kb + ((long)b * SEQ + (long)jt * 256) * DD, DD, DD / 32, lds, acc);
  const int t = threadIdx.x, lane = t & 63, w = t >> 6;
  const int wm = w >> 2, wn = w & 3, lr = lane & 15, lg = lane >> 4;
  bf16_t* Pt = P + ((long)b * SEQ + (long)c * 128) * (long)SEQ + (long)jt * 256;
  const bool hasDiag = (jt == (c >> 1));
  const int side = c & 1;
  const float scale = 0.02209708691207961f;  // 1/sqrt(2048)
  float* smf = (float*)lds;  // core quiesced LDS
#pragma unroll
  for (int mf = 0; mf < 4; ++mf)
#pragma unroll
    for (int reg = 0; reg < 4; ++reg) {
      int row = wm * 64 + mf * 16 + lg * 4 + reg;
#pragma unroll
      for (int nf = 0; nf < 4; ++nf) {
        int col = wn * 64 + nf * 16 + lr;
        float v = acc[mf][nf][reg];
        if (hasDiag && ((col >> 7) == side)) {
          int cc = col & 127;
          float sv = v * scale;
          smf[row * 128 + ((cc + row) & 127)] = (cc <= row) ? sv : -1e30f;
        } else {
          if (hasDiag && side == 0 && (col >> 7) == 1) v = 0.f;  // future chunk
          Pt[(long)row * SEQ + col] = (bf16_t)v;
        }
      }
    }
  if (hasDiag) {
    __syncthreads();
    if (t < 128) {
      int r = t;
      float mx = -1e30f;
      for (int cc = 0; cc <= r; ++cc) mx = fmaxf(mx, smf[r * 128 + ((cc + r) & 127)]);
      float s = 0.f;
      for (int cc = 0; cc <= r; ++cc) s += __expf(smf[r * 128 + ((cc + r) & 127)] - mx);
      float inv = 1.f / s;
      for (int cc = 0; cc < 128; ++cc) {
        float v = (cc <= r) ? __expf(smf[r * 128 + ((cc + r) & 127)] - mx) * inv : 0.f;
        Pt[(long)r * SEQ + side * 128 + cc] = (bf16_t)v;
      }
    }
  }
}

// --- GEMM2 (coreTB<2,4>, XCD-pinned nb): OutPre = (P @ V[0:K]) * gate -------
__global__ __launch_bounds__(512, 4) void k_gemm2(const bf16_t* __restrict__ P,
                                                  const bf16_t* __restrict__ Vt,
                                                  const bf16_t* __restrict__ G,
                                                  bf16_t* __restrict__ OutPre) {
  extern __shared__ bf16_t lds[];
  int bid = blockIdx.x;
  int nb = bid & 7;          // XCD-pinned: nb's 64 blocks share one L2 (4MB Vt)
  int tmp = bid >> 3;        // 0..63
  int mq = 31 - (tmp >> 1);  // longest-first within XCD
  int b = tmp & 1;
  f32x4 acc[4][4];
  coreTB<2, 4>(P + ((long)b * SEQ + (long)mq * 128) * (long)SEQ, SEQ,
               Vt + (long)b * DD * SEQ + (long)nb * 256 * SEQ, SEQ, (mq + 1) * 4,
               lds, acc);
  const int t = threadIdx.x, lane = t & 63, w = t >> 6;
  const int wm = w >> 2, wn = w & 3, lr = lane & 15, lg = lane >> 4;
#pragma unroll
  for (int mf = 0; mf < 4; ++mf)
#pragma unroll
    for (int reg = 0; reg < 4; ++reg) {
      long row = (long)b * SEQ + (long)mq * 128 + wm * 64 + mf * 16 + lg * 4 + reg;
#pragma unroll
      for (int nf = 0; nf < 4; ++nf) {
        long idx = row * DD + nb * 256 + wn * 64 + nf * 16 + lr;
        float g = (float)G[idx];
        OutPre[idx] = (bf16_t)(acc[mf][nf][reg] * g);
      }
    }
}

// --- GEMM3 (coreTB<2,4>): out = OutPre @ Wo + bo ----------------------------
__global__ __launch_bounds__(512, 4) void k_gemm3(const bf16_t* __restrict__ OutPre,
                                                  const bf16_t* __restrict__ Wot,
                                                  const float* __restrict__ bo,
                                                  float* __restrict__ out) {
  extern __shared__ bf16_t lds[];
  int mb = blockIdx.x >> 2, nb = blockIdx.x & 3;
  f32x4 acc[4][4];
  coreTB<2, 4>(OutPre + (long)mb * 128 * DD, DD, Wot + (long)nb * 256 * DD, DD,
               DD / 32, lds, acc);
  const int t = threadIdx.x, lane = t & 63, w = t >> 6;
  const int wm = w >> 2, wn = w & 3, lr = lane & 15, lg = lane >> 4;
  int colbase = nb * 256 + wn * 64;
  float b4[4];
#pragma unroll
  for (int nf = 0; nf < 4; ++nf) b4[nf] = bo[colbase + nf * 16 + lr];
#pragma unroll
  for (int mf = 0; mf < 4; ++mf)
#pragma unroll
    for (int reg = 0; reg < 4; ++reg) {
      long row = mb * 128 + wm * 64 + mf * 16 + lg * 4 + reg;
#pragma unroll
      for (int nf = 0; nf < 4; ++nf)
        out[row * HID + colbase + nf * 16 + lr] = acc[mf][nf][reg] + b4[nf];
    }
}

extern "C" void kernel_launch(void* const* d_in, const int* in_sizes, int n_in,
                              void* d_out, int out_size, void* d_ws, size_t ws_size,
                              hipStream_t stream) {
  const float* hs = (const float*)d_in[0];
  const float* Wq = (const float*)d_in[1];
  const float* bq = (const float*)d_in[2];
  const float* Wk = (const float*)d_in[3];
  const float* bk = (const float*)d_in[4];
  const float* Wv = (const float*)d_in[5];
  const float* bv = (const float*)d_in[6];
  const float* Wg = (const float*)d_in[7];
  const float* bg = (const float*)d_in[8];
  const float* Wo = (const float*)d_in[9];
  const float* bo = (const float*)d_in[10];
  float* out = (float*)d_out;

  char* ws = (char*)d_ws;
  const size_t MB = 1024 * 1024;
  bf16_t* P = (bf16_t*)(ws);            // [2][4096][4096] bf16, 64MB
  bf16_t* hsb = (bf16_t*)(ws);          // aliases P (dead before pair)
  bf16_t* Wt4 = (bf16_t*)(ws + 16 * MB);
  bf16_t* Wot = (bf16_t*)(ws + 64 * MB);
  bf16_t* QKVG = (bf16_t*)(ws + 68 * MB);
  bf16_t* Vt = (bf16_t*)(ws + 196 * MB);

  bf16_t* Qb = QKVG;
  bf16_t* Kbuf = QKVG + (long)BS * DD;
  bf16_t* Vbuf = QKVG + 2l * BS * DD;  // V row-major unused (V -> Vt directly)
  bf16_t* Gbuf = QKVG + 3l * BS * DD;
  bf16_t* OutPre = Vbuf;

  hipFuncSetAttribute((const void*)k_gemm_qkvg,
                      hipFuncAttributeMaxDynamicSharedMemorySize, LDS_TB);
  hipFuncSetAttribute((const void*)k_pair,
                      hipFuncAttributeMaxDynamicSharedMemorySize, LDS_TB);
  hipFuncSetAttribute((const void*)k_gemm2,
                      hipFuncAttributeMaxDynamicSharedMemorySize, LDS_TB);
  hipFuncSetAttribute((const void*)k_gemm3,
                      hipFuncAttributeMaxDynamicSharedMemorySize, LDS_TB);

  // 1. fused prep (hs cvt + Wq/Wk/Wv/Wg/Wo transposes)
  k_prep<<<dim3(32, 32, 6), 256, 0, stream>>>(hs, Wq, Wk, Wv, Wg, Wo, hsb, Wt4, Wot);

  // 2. QKVG projection (2048 blocks, 2 blk/CU; V fused -> Vt transposed)
  k_gemm_qkvg<<<2048, 512, LDS_TB, stream>>>(hsb, Wt4, bq, bk, bv, bg, QKVG, Vt);

  // 3. pairwise scores + fused diag softmax (544 blocks, 2 blk/CU)
  k_pair<<<dim3(272, 2), 512, LDS_TB, stream>>>(Qb, Kbuf, P);

  // 4. PV + gate (512 blocks; nb XCD-pinned, longest-first, 2 blk/CU)
  k_gemm2<<<512, 512, LDS_TB, stream>>>(P, Vt, Gbuf, OutPre);

  // 5. output projection (256 blocks, 2 blk/CU)
  k_gemm3<<<256, 512, LDS_TB, stream>>>(OutPre, Wot, bo, out);
}